// Round 3
// baseline (257.285 us; speedup 1.0000x reference)
//
#include <hip/hip_runtime.h>

constexpr int HW = 1024 * 1024;
constexpr int NB = 16;
constexpr float EPS = 1e-6f;
constexpr int BLOCKS_PER_BATCH = 128;  // 2048 blocks total
constexpr int THREADS = 256;
constexpr int NVEC    = HW / 4;                      // 262144 float4 per batch
constexpr int TPB     = BLOCKS_PER_BATCH * THREADS;  // 32768 threads per batch
constexpr int U       = NVEC / TPB;                  // 8 windows per thread (exact)

// Per-batch partial sums: ws[b*4 + {0,1,2,3}] = {Sp, Spp, St, Stp}
__global__ __launch_bounds__(THREADS, 4) void dice_partial(
        const float* __restrict__ logits,
        const int*   __restrict__ labels,
        float*       __restrict__ ws) {
    const int b   = blockIdx.x >> 7;         // / BLOCKS_PER_BATCH
    const int blk = blockIdx.x & 127;        // % BLOCKS_PER_BATCH

    const float4* __restrict__ L0 = reinterpret_cast<const float4*>(logits + (size_t)b * 2 * HW);
    const float4* __restrict__ L1 = reinterpret_cast<const float4*>(logits + (size_t)b * 2 * HW + HW);
    const int4*   __restrict__ LB = reinterpret_cast<const int4*>(labels + (size_t)b * HW);

    const int base = blk * THREADS + threadIdx.x;   // [0, 32768)

    // Issue ALL 24 loads back-to-back: 96 VGPRs of payload in flight per lane.
    float4 a[U], c[U];
    int4   t[U];
    #pragma unroll
    for (int u = 0; u < U; ++u) {
        const int i = base + u * TPB;
        a[u] = L0[i];
        c[u] = L1[i];
        t[u] = LB[i];
    }

    float sp = 0.f, spp = 0.f, st = 0.f, stp = 0.f;
    #pragma unroll
    for (int u = 0; u < U; ++u) {
        float p, tf;
        p = 1.f / (1.f + __expf(a[u].x - c[u].x)); tf = (float)t[u].x;
        sp += p; spp = fmaf(p, p, spp); st += tf; stp = fmaf(tf, p, stp);
        p = 1.f / (1.f + __expf(a[u].y - c[u].y)); tf = (float)t[u].y;
        sp += p; spp = fmaf(p, p, spp); st += tf; stp = fmaf(tf, p, stp);
        p = 1.f / (1.f + __expf(a[u].z - c[u].z)); tf = (float)t[u].z;
        sp += p; spp = fmaf(p, p, spp); st += tf; stp = fmaf(tf, p, stp);
        p = 1.f / (1.f + __expf(a[u].w - c[u].w)); tf = (float)t[u].w;
        sp += p; spp = fmaf(p, p, spp); st += tf; stp = fmaf(tf, p, stp);
    }

    // wave-64 shuffle reduction
    #pragma unroll
    for (int off = 32; off > 0; off >>= 1) {
        sp  += __shfl_down(sp,  off);
        spp += __shfl_down(spp, off);
        st  += __shfl_down(st,  off);
        stp += __shfl_down(stp, off);
    }

    __shared__ float red[4][4];   // [wave][component]
    const int wave = threadIdx.x >> 6;
    const int lane = threadIdx.x & 63;
    if (lane == 0) {
        red[wave][0] = sp; red[wave][1] = spp; red[wave][2] = st; red[wave][3] = stp;
    }
    __syncthreads();
    if (threadIdx.x == 0) {
        float a0 = 0.f, a1 = 0.f, a2 = 0.f, a3 = 0.f;
        #pragma unroll
        for (int w = 0; w < 4; ++w) {
            a0 += red[w][0]; a1 += red[w][1]; a2 += red[w][2]; a3 += red[w][3];
        }
        atomicAdd(&ws[b * 4 + 0], a0);
        atomicAdd(&ws[b * 4 + 1], a1);
        atomicAdd(&ws[b * 4 + 2], a2);
        atomicAdd(&ws[b * 4 + 3], a3);
    }
}

__global__ void dice_final(const float* __restrict__ ws, float* __restrict__ out) {
    float local = 0.f;
    const int b = threadIdx.x;
    if (b < NB) {
        const float Sp  = ws[b * 4 + 0];
        const float Spp = ws[b * 4 + 1];
        const float St  = ws[b * 4 + 2];
        const float Stp = ws[b * 4 + 3];
        const float N = (float)HW;

        const float num1 = 2.f * Stp;
        const float den1 = Spp + St;
        const float num0 = 2.f * (N - St - Sp + Stp);
        const float den0 = (N - 2.f * Sp + Spp) + (N - St);

        local = num0 / (den0 + EPS) + num1 / (den1 + EPS);
    }
    #pragma unroll
    for (int off = 32; off > 0; off >>= 1) local += __shfl_down(local, off);
    if (threadIdx.x == 0) out[0] = 1.f - local / 32.f;
}

extern "C" void kernel_launch(void* const* d_in, const int* in_sizes, int n_in,
                              void* d_out, int out_size, void* d_ws, size_t ws_size,
                              hipStream_t stream) {
    const float* logits = (const float*)d_in[0];
    const int*   labels = (const int*)d_in[1];
    float* out = (float*)d_out;
    float* ws  = (float*)d_ws;

    hipMemsetAsync(ws, 0, NB * 4 * sizeof(float), stream);
    dice_partial<<<NB * BLOCKS_PER_BATCH, THREADS, 0, stream>>>(logits, labels, ws);
    dice_final<<<1, 64, 0, stream>>>(ws, out);
}

// Round 5
// 221.109 us; speedup vs baseline: 1.1636x; 1.1636x over previous
//
#include <hip/hip_runtime.h>

constexpr int HW = 1024 * 1024;
constexpr int NB = 16;
constexpr float EPS = 1e-6f;
constexpr int BLOCKS_PER_BATCH = 128;  // 2048 blocks total -> 8 blocks/CU
constexpr int THREADS = 256;
constexpr int NVEC    = HW / 4;                      // 262144 vec4 per batch
constexpr int TPB     = BLOCKS_PER_BATCH * THREADS;  // 32768 threads per batch
constexpr int U       = NVEC / TPB;                  // 8 windows per thread (exact)
constexpr int NBLK    = NB * BLOCKS_PER_BATCH;       // 2048

typedef float f32x4 __attribute__((ext_vector_type(4)));
typedef int   i32x4 __attribute__((ext_vector_type(4)));

// Stage 1: per-block partials -> ws4[gid] = {Sp, Spp, St, Stp}. No atomics.
__global__ __launch_bounds__(THREADS, 8) void dice_partial(
        const float* __restrict__ logits,
        const int*   __restrict__ labels,
        f32x4*       __restrict__ ws4) {
    const int b   = blockIdx.x >> 7;         // / BLOCKS_PER_BATCH
    const int blk = blockIdx.x & 127;        // % BLOCKS_PER_BATCH

    const f32x4* __restrict__ L0 = reinterpret_cast<const f32x4*>(logits + (size_t)b * 2 * HW);
    const f32x4* __restrict__ L1 = reinterpret_cast<const f32x4*>(logits + (size_t)b * 2 * HW + HW);
    const i32x4* __restrict__ LB = reinterpret_cast<const i32x4*>(labels + (size_t)b * HW);

    const int base = blk * THREADS + threadIdx.x;   // [0, 32768)

    float sp = 0.f, spp = 0.f, st = 0.f, stp = 0.f;

    #pragma unroll
    for (int u = 0; u < U; ++u) {
        const int i = base + u * TPB;
        f32x4 a = __builtin_nontemporal_load(&L0[i]);   // class-0 logits
        f32x4 c = __builtin_nontemporal_load(&L1[i]);   // class-1 logits
        i32x4 t = __builtin_nontemporal_load(&LB[i]);   // labels in {0,1}

        #pragma unroll
        for (int k = 0; k < 4; ++k) {
            const float p  = 1.f / (1.f + __expf(a[k] - c[k]));
            const float tf = (float)t[k];
            sp += p; spp = fmaf(p, p, spp); st += tf; stp = fmaf(tf, p, stp);
        }
    }

    // wave-64 shuffle reduction
    #pragma unroll
    for (int off = 32; off > 0; off >>= 1) {
        sp  += __shfl_down(sp,  off);
        spp += __shfl_down(spp, off);
        st  += __shfl_down(st,  off);
        stp += __shfl_down(stp, off);
    }

    __shared__ float red[4][4];   // [wave][component]
    const int wave = threadIdx.x >> 6;
    const int lane = threadIdx.x & 63;
    if (lane == 0) {
        red[wave][0] = sp; red[wave][1] = spp; red[wave][2] = st; red[wave][3] = stp;
    }
    __syncthreads();
    if (threadIdx.x == 0) {
        f32x4 r;
        r.x = red[0][0] + red[1][0] + red[2][0] + red[3][0];
        r.y = red[0][1] + red[1][1] + red[2][1] + red[3][1];
        r.z = red[0][2] + red[1][2] + red[2][2] + red[3][2];
        r.w = red[0][3] + red[1][3] + red[2][3] + red[3][3];
        ws4[blockIdx.x] = r;   // plain store, distinct slot per block
    }
}

// Stage 2: one block per batch, 128 threads fold 128 partials -> term_b.
__global__ __launch_bounds__(128) void dice_batch(
        const f32x4* __restrict__ ws4,
        float*       __restrict__ terms) {
    const int b = blockIdx.x;
    f32x4 v = ws4[b * BLOCKS_PER_BATCH + threadIdx.x];

    #pragma unroll
    for (int off = 32; off > 0; off >>= 1) {
        v.x += __shfl_down(v.x, off);
        v.y += __shfl_down(v.y, off);
        v.z += __shfl_down(v.z, off);
        v.w += __shfl_down(v.w, off);
    }

    __shared__ f32x4 red[2];
    const int wave = threadIdx.x >> 6;
    const int lane = threadIdx.x & 63;
    if (lane == 0) red[wave] = v;
    __syncthreads();
    if (threadIdx.x == 0) {
        const float Sp  = red[0].x + red[1].x;
        const float Spp = red[0].y + red[1].y;
        const float St  = red[0].z + red[1].z;
        const float Stp = red[0].w + red[1].w;
        const float N = (float)HW;

        const float num1 = 2.f * Stp;
        const float den1 = Spp + St;
        const float num0 = 2.f * (N - St - Sp + Stp);
        const float den0 = (N - 2.f * Sp + Spp) + (N - St);

        terms[b] = num0 / (den0 + EPS) + num1 / (den1 + EPS);
    }
}

// Stage 3: fold the 16 batch terms into the scalar loss.
__global__ void dice_final(const float* __restrict__ terms, float* __restrict__ out) {
    float local = (threadIdx.x < NB) ? terms[threadIdx.x] : 0.f;
    #pragma unroll
    for (int off = 32; off > 0; off >>= 1) local += __shfl_down(local, off);
    if (threadIdx.x == 0) out[0] = 1.f - local / 32.f;
}

extern "C" void kernel_launch(void* const* d_in, const int* in_sizes, int n_in,
                              void* d_out, int out_size, void* d_ws, size_t ws_size,
                              hipStream_t stream) {
    const float* logits = (const float*)d_in[0];
    const int*   labels = (const int*)d_in[1];
    float* out   = (float*)d_out;
    f32x4* ws4   = (f32x4*)d_ws;                       // 2048 vec4 = 32 KB
    float* terms = (float*)d_ws + NBLK * 4;            // 16 floats after partials

    dice_partial<<<NBLK, THREADS, 0, stream>>>(logits, labels, ws4);
    dice_batch<<<NB, 128, 0, stream>>>(ws4, terms);
    dice_final<<<1, 64, 0, stream>>>(terms, out);
}

// Round 6
// 215.860 us; speedup vs baseline: 1.1919x; 1.0243x over previous
//
#include <hip/hip_runtime.h>

constexpr int HW = 1024 * 1024;
constexpr int NB = 16;
constexpr float EPS = 1e-6f;
constexpr int BLOCKS_PER_BATCH = 128;  // 2048 blocks total -> 8 blocks/CU
constexpr int THREADS = 256;
constexpr int NVEC    = HW / 4;                      // 262144 vec4 per batch
constexpr int TPB     = BLOCKS_PER_BATCH * THREADS;  // 32768 threads per batch
constexpr int U       = NVEC / TPB;                  // 8 windows per thread (exact)
constexpr int NBLK    = NB * BLOCKS_PER_BATCH;       // 2048

typedef float f32x4 __attribute__((ext_vector_type(4)));
typedef int   i32x4 __attribute__((ext_vector_type(4)));

// Stage 1: per-block partials -> ws4[gid] = {Sp, Spp, St, Stp}. No atomics.
// Software-pipelined: window u+2's loads are issued BEFORE window u is
// consumed, so ~9 nt-loads stay in flight per thread.
__global__ __launch_bounds__(THREADS, 8) void dice_partial(
        const float* __restrict__ logits,
        const int*   __restrict__ labels,
        f32x4*       __restrict__ ws4) {
    const int b   = blockIdx.x >> 7;         // / BLOCKS_PER_BATCH
    const int blk = blockIdx.x & 127;        // % BLOCKS_PER_BATCH

    const f32x4* __restrict__ L0 = reinterpret_cast<const f32x4*>(logits + (size_t)b * 2 * HW);
    const f32x4* __restrict__ L1 = reinterpret_cast<const f32x4*>(logits + (size_t)b * 2 * HW + HW);
    const i32x4* __restrict__ LB = reinterpret_cast<const i32x4*>(labels + (size_t)b * HW);

    const int base = blk * THREADS + threadIdx.x;   // [0, 32768)

    f32x4 a[2], c[2];
    i32x4 t[2];
    a[0] = __builtin_nontemporal_load(&L0[base]);
    c[0] = __builtin_nontemporal_load(&L1[base]);
    t[0] = __builtin_nontemporal_load(&LB[base]);
    a[1] = __builtin_nontemporal_load(&L0[base + TPB]);
    c[1] = __builtin_nontemporal_load(&L1[base + TPB]);
    t[1] = __builtin_nontemporal_load(&LB[base + TPB]);

    float sp = 0.f, spp = 0.f, st = 0.f, stp = 0.f;

    #pragma unroll
    for (int u = 0; u < U; ++u) {
        const int cur = u & 1;
        f32x4 an, cn;
        i32x4 tn;
        const bool pf = (u + 2 < U);
        if (pf) {
            const int i = base + (u + 2) * TPB;
            an = __builtin_nontemporal_load(&L0[i]);
            cn = __builtin_nontemporal_load(&L1[i]);
            tn = __builtin_nontemporal_load(&LB[i]);
        }
        #pragma unroll
        for (int k = 0; k < 4; ++k) {
            const float p  = 1.f / (1.f + __expf(a[cur][k] - c[cur][k]));
            const float tf = (float)t[cur][k];
            sp += p; spp = fmaf(p, p, spp); st += tf; stp = fmaf(tf, p, stp);
        }
        if (pf) { a[cur] = an; c[cur] = cn; t[cur] = tn; }
    }

    // wave-64 shuffle reduction
    #pragma unroll
    for (int off = 32; off > 0; off >>= 1) {
        sp  += __shfl_down(sp,  off);
        spp += __shfl_down(spp, off);
        st  += __shfl_down(st,  off);
        stp += __shfl_down(stp, off);
    }

    __shared__ float red[4][4];   // [wave][component]
    const int wave = threadIdx.x >> 6;
    const int lane = threadIdx.x & 63;
    if (lane == 0) {
        red[wave][0] = sp; red[wave][1] = spp; red[wave][2] = st; red[wave][3] = stp;
    }
    __syncthreads();
    if (threadIdx.x == 0) {
        f32x4 r;
        r.x = red[0][0] + red[1][0] + red[2][0] + red[3][0];
        r.y = red[0][1] + red[1][1] + red[2][1] + red[3][1];
        r.z = red[0][2] + red[1][2] + red[2][2] + red[3][2];
        r.w = red[0][3] + red[1][3] + red[2][3] + red[3][3];
        ws4[blockIdx.x] = r;   // plain store, distinct slot per block
    }
}

// Stage 2 (merged): one block, 1024 threads = 16 waves; wave w folds batch w's
// 128 partials and computes its dice term; wave 0 then folds the 16 terms.
__global__ __launch_bounds__(1024) void dice_reduce(
        const f32x4* __restrict__ ws4,
        float*       __restrict__ out) {
    const int wave = threadIdx.x >> 6;   // 0..15 == batch index
    const int lane = threadIdx.x & 63;

    f32x4 v = ws4[wave * BLOCKS_PER_BATCH + lane]
            + ws4[wave * BLOCKS_PER_BATCH + 64 + lane];

    #pragma unroll
    for (int off = 32; off > 0; off >>= 1) {
        v.x += __shfl_down(v.x, off);
        v.y += __shfl_down(v.y, off);
        v.z += __shfl_down(v.z, off);
        v.w += __shfl_down(v.w, off);
    }

    __shared__ float terms[NB];
    if (lane == 0) {
        const float Sp  = v.x;
        const float Spp = v.y;
        const float St  = v.z;
        const float Stp = v.w;
        const float N = (float)HW;

        const float num1 = 2.f * Stp;
        const float den1 = Spp + St;
        const float num0 = 2.f * (N - St - Sp + Stp);
        const float den0 = (N - 2.f * Sp + Spp) + (N - St);

        terms[wave] = num0 / (den0 + EPS) + num1 / (den1 + EPS);
    }
    __syncthreads();
    if (threadIdx.x == 0) {
        float s = 0.f;
        #pragma unroll
        for (int i = 0; i < NB; ++i) s += terms[i];
        out[0] = 1.f - s / 32.f;
    }
}

extern "C" void kernel_launch(void* const* d_in, const int* in_sizes, int n_in,
                              void* d_out, int out_size, void* d_ws, size_t ws_size,
                              hipStream_t stream) {
    const float* logits = (const float*)d_in[0];
    const int*   labels = (const int*)d_in[1];
    float* out = (float*)d_out;
    f32x4* ws4 = (f32x4*)d_ws;                       // 2048 vec4 = 32 KB

    dice_partial<<<NBLK, THREADS, 0, stream>>>(logits, labels, ws4);
    dice_reduce<<<1, 1024, 0, stream>>>(ws4, out);
}